// Round 8
// baseline (2624.159 us; speedup 1.0000x reference)
//
#include <hip/hip_runtime.h>
#include <stdint.h>
#include <stddef.h>

// ---------------------------------------------------------------------------
// DMPNN on MI355X — bf16-MFMA round updates (round 8).
// Evidence r7: tier-1 (stored h0) runs; k_update was fp32-VALU-bound (MfmaUtil 0,
// VALUBusy 61%, 19% cycles in LDS bank conflicts, HBM 11%). This round moves the
// two edge GEMMs to mfma_f32_16x16x32_bf16 with padded-LDS conflict-free frags.
// h, h0, sum0-gather plumbing unchanged (sum0 stays fp32; L3 absorbs the gather).
// ---------------------------------------------------------------------------

typedef unsigned short u16;
typedef u16 u16x2 __attribute__((ext_vector_type(2)));
typedef u16 u16x4 __attribute__((ext_vector_type(4)));
typedef u16 u16x8 __attribute__((ext_vector_type(8)));
typedef short s16x8 __attribute__((ext_vector_type(8)));
typedef float f32x4_ __attribute__((ext_vector_type(4)));

__device__ __forceinline__ float lk(float x) { return x >= 0.f ? x : 0.01f * x; }

__device__ __forceinline__ float bf2f(u16 u) {
    union { uint32_t i; float f; } v; v.i = ((uint32_t)u) << 16; return v.f;
}
__device__ __forceinline__ u16 f2bf(float f) {   // round-to-nearest-even
    union { float f; uint32_t i; } v; v.f = f;
    uint32_t r = v.i + 0x7FFFu + ((v.i >> 16) & 1u);
    return (u16)(r >> 16);
}

// ---------------- utility ----------------
__global__ void k_zero_i32(int* __restrict__ p, int n) {
    int i = blockIdx.x * blockDim.x + threadIdx.x;
    if (i < n) p[i] = 0;
}
__global__ void k_zero_f32(float* __restrict__ p, int n) {
    int i = blockIdx.x * blockDim.x + threadIdx.x;
    if (i < n) p[i] = 0.f;
}

// Transpose-convert W_upd [K=128][N=128] fp32 -> wTg [n][k] bf16 (dense 128x128)
__global__ void k_prep_wu(const float* __restrict__ W, u16* __restrict__ wTg) {
    int i = blockIdx.x * 256 + threadIdx.x;
    if (i < 128 * 128) { int n = i >> 7, k = i & 127; wTg[i] = f2bf(W[k * 128 + n]); }
}
// W_edge [K=80][N=128] fp32 -> weTg [n][k=0..95] bf16, zero pad k>=80
__global__ void k_prep_we(const float* __restrict__ W, u16* __restrict__ weTg) {
    int i = blockIdx.x * 256 + threadIdx.x;
    if (i < 128 * 96) {
        int n = i / 96, k = i - n * 96;
        weTg[i] = (k < 80) ? f2bf(W[k * 128 + n]) : (u16)0;
    }
}

// ---------------- CSR build ----------------
__global__ void k_count(const int* __restrict__ dst, int* __restrict__ counts, int E) {
    int i = blockIdx.x * blockDim.x + threadIdx.x;
    if (i < E) atomicAdd(&counts[dst[i]], 1);
}

__global__ __launch_bounds__(1024) void k_scan(const int* __restrict__ counts,
                                               int* __restrict__ off, int Nn) {
    __shared__ int buf[1024];
    __shared__ int carry_s;
    int t = threadIdx.x;
    if (t == 0) carry_s = 0;
    __syncthreads();
    for (int base = 0; base < Nn; base += 8192) {
        int v[8]; int s = 0;
#pragma unroll
        for (int i = 0; i < 8; ++i) {
            int idx = base + t * 8 + i;
            v[i] = (idx < Nn) ? counts[idx] : 0;
            s += v[i];
        }
        int x = s;
        for (int o = 1; o < 1024; o <<= 1) {
            buf[t] = x; __syncthreads();
            if (t >= o) x += buf[t - o];
            __syncthreads();
        }
        int excl = carry_s + x - s;
#pragma unroll
        for (int i = 0; i < 8; ++i) {
            int idx = base + t * 8 + i;
            if (idx < Nn) off[idx] = excl;
            excl += v[i];
        }
        __syncthreads();
        if (t == 1023) carry_s += x;
        __syncthreads();
    }
    if (t == 0) off[Nn] = carry_s;
}

__global__ void k_fill(const int* __restrict__ dst, const int* __restrict__ off,
                       int* __restrict__ cursor, int* __restrict__ eidx, int E) {
    int i = blockIdx.x * blockDim.x + threadIdx.x;
    if (i < E) {
        int d = dst[i];
        int p = atomicAdd(&cursor[d], 1);
        eidx[off[d] + p] = i;
    }
}

// ---------------- segment sum over bf16 h rows (per-node wave gather) ---------
__global__ __launch_bounds__(256) void k_segsum(const u16* __restrict__ h,
                                                const int* __restrict__ off,
                                                const int* __restrict__ eidx,
                                                float* __restrict__ out, int Nn) {
    int wid = threadIdx.x >> 6;
    int lane = threadIdx.x & 63;
    int n = blockIdx.x * 4 + wid;
    if (n >= Nn) return;
    int lo = off[n], hi = off[n + 1];
    float ax = 0.f, ay = 0.f;
    int j = lo;
    for (; j + 3 < hi; j += 4) {
        int ea = eidx[j], eb = eidx[j + 1], ec = eidx[j + 2], ed = eidx[j + 3];
        u16x2 va = *(const u16x2*)(h + (size_t)ea * 128 + lane * 2);
        u16x2 vb = *(const u16x2*)(h + (size_t)eb * 128 + lane * 2);
        u16x2 vc = *(const u16x2*)(h + (size_t)ec * 128 + lane * 2);
        u16x2 vd = *(const u16x2*)(h + (size_t)ed * 128 + lane * 2);
        ax += (bf2f(va[0]) + bf2f(vb[0])) + (bf2f(vc[0]) + bf2f(vd[0]));
        ay += (bf2f(va[1]) + bf2f(vb[1])) + (bf2f(vc[1]) + bf2f(vd[1]));
    }
    for (; j < hi; ++j) {
        int ea = eidx[j];
        u16x2 va = *(const u16x2*)(h + (size_t)ea * 128 + lane * 2);
        ax += bf2f(va[0]); ay += bf2f(va[1]);
    }
    float2 r; r.x = ax; r.y = ay;
    *(float2*)(out + (size_t)n * 128 + lane * 2) = r;
}

// ===================== MFMA tier-1 kernels =====================
// LDS rows padded: K=128 arrays use stride 136 bf16 (272 B: dword-stride 68 ≡ 4
// mod 32 → conflict-free per 8-lane phase). K=96 arrays use stride 104 (208 B,
// dword-stride 52 ≡ 20 mod 32, gcd(20,32)=4 → conflict-free per phase).

// ---- edge init: h = h0 = leaky(bf16([nf[src]|ef]) @ bf16(W_edge)) ----
__global__ __launch_bounds__(256) void k_edge_init_mfma(
    const float* __restrict__ node_feat, const float* __restrict__ edge_feat,
    const int* __restrict__ src, const u16* __restrict__ weTg,
    u16* __restrict__ h0, u16* __restrict__ h) {
    __shared__ u16 mwe[64][104];    // x0 tile, K padded to 96
    __shared__ u16 wTe[128][104];   // W_edge^T [ncol][k]
    const int t = threadIdx.x;
    const int e0 = blockIdx.x * 64;
    // stage wTe from preconverted global (dense [128][96])
    {
        int n = t >> 1, half = t & 1;
        const u16* gsrc = weTg + n * 96 + half * 48;
        u16* ldst = &wTe[n][half * 48];
#pragma unroll
        for (int i = 0; i < 6; ++i)
            *(u16x8*)(ldst + i * 8) = *(const u16x8*)(gsrc + i * 8);
    }
    // stage x0 = [nf[src] | ef] as bf16
    {
        int rloc = t & 63, part = t >> 6;
        int e = e0 + rloc;
        int s = src[e];
        const float* nf = node_feat + (size_t)s * 64;
        const float* ef = edge_feat + (size_t)e * 16;
#pragma unroll
        for (int i = 0; i < 5; ++i) {
            int f = part * 20 + i * 4;
            float4 v;
            if (f < 64) v = *(const float4*)(nf + f);
            else        v = *(const float4*)(ef + (f - 64));
            u16x4 o; o[0] = f2bf(v.x); o[1] = f2bf(v.y); o[2] = f2bf(v.z); o[3] = f2bf(v.w);
            *(u16x4*)(&mwe[rloc][f]) = o;
        }
    }
    // zero-pad k = 80..95
    {
        int rr = t >> 2, part = t & 3;
        u16x4 z = {0, 0, 0, 0};
        *(u16x4*)(&mwe[rr][80 + part * 4]) = z;
    }
    __syncthreads();
    // MFMA: wave w owns edge rows w*16..w*16+15, all 8 n-tiles
    const int w = t >> 6, l = t & 63;
    const int er = l & 15, kg = l >> 4;
    f32x4_ acc[8];
#pragma unroll
    for (int nt = 0; nt < 8; ++nt) { f32x4_ z = {0.f, 0.f, 0.f, 0.f}; acc[nt] = z; }
#pragma unroll
    for (int ks = 0; ks < 3; ++ks) {
        s16x8 bfrag = *(const s16x8*)(&mwe[w * 16 + er][ks * 32 + kg * 8]);
#pragma unroll
        for (int nt = 0; nt < 8; ++nt) {
            s16x8 afrag = *(const s16x8*)(&wTe[nt * 16 + er][ks * 32 + kg * 8]);
            acc[nt] = __builtin_amdgcn_mfma_f32_16x16x32_bf16(afrag, bfrag, acc[nt], 0, 0, 0);
        }
    }
    // epilogue: lane holds D[ncol = nt*16+kg*4+r][edge = e0+w*16+er]
    {
        size_t gedge = (size_t)(e0 + w * 16 + er);
        u16* hr = h + gedge * 128;
        u16* h0r = h0 + gedge * 128;
#pragma unroll
        for (int nt = 0; nt < 8; ++nt) {
            int nc = nt * 16 + kg * 4;
            u16x4 o;
#pragma unroll
            for (int r = 0; r < 4; ++r) o[r] = f2bf(lk(acc[nt][r]));
            *(u16x4*)(hr + nc) = o;
            *(u16x4*)(h0r + nc) = o;
        }
    }
}

// ---- in-place paired round update, MFMA ----
// h[gedge] = bf16( leaky( (sum0[src]-h[rev]) @ W_upd + h0[gedge] ) )
__global__ __launch_bounds__(256) void k_update_mfma(
    u16* __restrict__ h, const u16* __restrict__ h0,
    const float* __restrict__ sum0, const int* __restrict__ src,
    const int* __restrict__ rev, const u16* __restrict__ wTg) {
    __shared__ u16 mw[64][136];     // m tile bf16
    __shared__ u16 wT[128][136];    // W_upd^T [ncol][k]
    __shared__ int eid[64];
    const int t = threadIdx.x;
    const int p0 = blockIdx.x * 32;
    // stage wT (global preconverted dense [128][128])
    {
        int wr = t >> 1, half = t & 1;
        const u16* gsrc = wTg + wr * 128 + half * 64;
        u16* ldst = &wT[wr][half * 64];
#pragma unroll
        for (int i = 0; i < 8; ++i)
            *(u16x8*)(ldst + i * 8) = *(const u16x8*)(gsrc + i * 8);
    }
    // stage m = sum0[src[gedge]] - h[partner]  (pair-closed row set -> in-place safe)
    {
        int rr = t >> 2, part = t & 3;
        int gedge, partner;
        if (rr < 32) { gedge = p0 + rr;        partner = rev[gedge]; }
        else         { partner = p0 + rr - 32; gedge = rev[partner]; }
        if (part == 0) eid[rr] = gedge;
        int s = src[gedge];
        const float* sp = sum0 + (size_t)s * 128 + part * 32;
        const u16* hp = h + (size_t)partner * 128 + part * 32;
#pragma unroll
        for (int i = 0; i < 4; ++i) {
            float4 a0 = *(const float4*)(sp + i * 8);
            float4 a1 = *(const float4*)(sp + i * 8 + 4);
            u16x8 b = *(const u16x8*)(hp + i * 8);
            u16x8 o;
            o[0] = f2bf(a0.x - bf2f(b[0]));
            o[1] = f2bf(a0.y - bf2f(b[1]));
            o[2] = f2bf(a0.z - bf2f(b[2]));
            o[3] = f2bf(a0.w - bf2f(b[3]));
            o[4] = f2bf(a1.x - bf2f(b[4]));
            o[5] = f2bf(a1.y - bf2f(b[5]));
            o[6] = f2bf(a1.z - bf2f(b[6]));
            o[7] = f2bf(a1.w - bf2f(b[7]));
            *(u16x8*)(&mw[rr][part * 32 + i * 8]) = o;
        }
    }
    __syncthreads();
    // MFMA: wave w owns edge rows w*16..w*16+15, all 8 n-tiles, K=128 (4 steps)
    const int w = t >> 6, l = t & 63;
    const int er = l & 15, kg = l >> 4;
    f32x4_ acc[8];
#pragma unroll
    for (int nt = 0; nt < 8; ++nt) { f32x4_ z = {0.f, 0.f, 0.f, 0.f}; acc[nt] = z; }
#pragma unroll
    for (int ks = 0; ks < 4; ++ks) {
        s16x8 bfrag = *(const s16x8*)(&mw[w * 16 + er][ks * 32 + kg * 8]);
#pragma unroll
        for (int nt = 0; nt < 8; ++nt) {
            s16x8 afrag = *(const s16x8*)(&wT[nt * 16 + er][ks * 32 + kg * 8]);
            acc[nt] = __builtin_amdgcn_mfma_f32_16x16x32_bf16(afrag, bfrag, acc[nt], 0, 0, 0);
        }
    }
    // epilogue: += h0, leaky, bf16, store (rows owned exclusively by this block)
    {
        int gedge = eid[w * 16 + er];
        u16* hr = h + (size_t)gedge * 128;
        const u16* h0r = h0 + (size_t)gedge * 128;
#pragma unroll
        for (int nt = 0; nt < 8; ++nt) {
            int nc = nt * 16 + kg * 4;
            u16x4 p = *(const u16x4*)(h0r + nc);
            u16x4 o;
#pragma unroll
            for (int r = 0; r < 4; ++r) o[r] = f2bf(lk(acc[nt][r] + bf2f(p[r])));
            *(u16x4*)(hr + nc) = o;
        }
    }
}

// ===================== fp32 fallback kernels (tier-2) =====================
#define KROW(i, m)                                                                 \
    acc[i][0] = fmaf(m, w0.x, acc[i][0]); acc[i][1] = fmaf(m, w0.y, acc[i][1]);    \
    acc[i][2] = fmaf(m, w0.z, acc[i][2]); acc[i][3] = fmaf(m, w0.w, acc[i][3]);    \
    acc[i][4] = fmaf(m, w1.x, acc[i][4]); acc[i][5] = fmaf(m, w1.y, acc[i][5]);    \
    acc[i][6] = fmaf(m, w1.z, acc[i][6]); acc[i][7] = fmaf(m, w1.w, acc[i][7]);

#define KSTEP(ARR, kk, kabs)                                                       \
    {                                                                              \
        const float m0 = ARR[et4 + 0][kabs];                                       \
        const float m1 = ARR[et4 + 1][kabs];                                       \
        const float m2 = ARR[et4 + 2][kabs];                                       \
        const float m3 = ARR[et4 + 3][kabs];                                       \
        const float4 w0 = *(const float4*)(&w_lds[(kk) * 128 + ct8]);              \
        const float4 w1 = *(const float4*)(&w_lds[(kk) * 128 + ct8 + 4]);          \
        KROW(0, m0) KROW(1, m1) KROW(2, m2) KROW(3, m3)                            \
    }

__global__ __launch_bounds__(256) void k_edge_init_f32(
    const float* __restrict__ node_feat, const float* __restrict__ edge_feat,
    const int* __restrict__ src, const float* __restrict__ W, u16* __restrict__ h) {
    __shared__ float in_lds[64][84];
    __shared__ float w_lds[16 * 128];
    const int t = threadIdx.x;
    const int e0 = blockIdx.x * 64;
    {
        int rloc = t & 63, part = t >> 6;
        int e = e0 + rloc;
        int s = src[e];
        const float* nf = node_feat + (size_t)s * 64;
        const float* ef = edge_feat + (size_t)e * 16;
#pragma unroll
        for (int i = 0; i < 5; ++i) {
            int f = part * 20 + i * 4;
            float4 v;
            if (f < 64) v = *(const float4*)(nf + f);
            else        v = *(const float4*)(ef + (f - 64));
            *(float4*)(&in_lds[rloc][f]) = v;
        }
    }
    float acc[4][8];
#pragma unroll
    for (int i = 0; i < 4; ++i)
#pragma unroll
        for (int j = 0; j < 8; ++j) acc[i][j] = 0.f;
    const int et4 = (t >> 4) * 4;
    const int ct8 = (t & 15) * 8;
    for (int kc = 0; kc < 80; kc += 16) {
        __syncthreads();
#pragma unroll
        for (int i = 0; i < 2; ++i) {
            int f4 = t + i * 256;
            *(float4*)(&w_lds[f4 * 4]) = *(const float4*)(W + (size_t)kc * 128 + (size_t)f4 * 4);
        }
        __syncthreads();
#pragma unroll 8
        for (int k = 0; k < 16; ++k) { KSTEP(in_lds, k, kc + k) }
    }
#pragma unroll
    for (int i = 0; i < 4; ++i) {
        size_t base = ((size_t)e0 + et4 + i) * 128 + ct8;
        u16x8 o;
#pragma unroll
        for (int j = 0; j < 8; ++j) o[j] = f2bf(lk(acc[i][j]));
        *(u16x8*)(h + base) = o;
    }
}

__global__ __launch_bounds__(256) void k_update_f32_recomp(
    u16* __restrict__ h, const float* __restrict__ sum0,
    const int* __restrict__ src, const int* __restrict__ rev,
    const float* __restrict__ Wu, const float* __restrict__ node_feat,
    const float* __restrict__ edge_feat, const float* __restrict__ We) {
    __shared__ float stage[64][132];
    __shared__ float w_lds[32 * 128];
    __shared__ int eid_lds[64];
    const int t = threadIdx.x;
    const int p0 = blockIdx.x * 32;
    const int et4 = (t >> 4) * 4;
    const int ct8 = (t & 15) * 8;
    float acc[4][8];
    float h0reg[4][8];
    {
        int rloc = t & 63, part = t >> 6;
        int gedge = (rloc < 32) ? (p0 + rloc) : rev[p0 + rloc - 32];
        if (part == 0) eid_lds[rloc] = gedge;
        int s = src[gedge];
        const float* nf = node_feat + (size_t)s * 64;
        const float* ef = edge_feat + (size_t)gedge * 16;
#pragma unroll
        for (int i = 0; i < 5; ++i) {
            int f = part * 20 + i * 4;
            float4 v;
            if (f < 64) v = *(const float4*)(nf + f);
            else        v = *(const float4*)(ef + (f - 64));
            *(float4*)(&stage[rloc][f]) = v;
        }
    }
#pragma unroll
    for (int i = 0; i < 4; ++i)
#pragma unroll
        for (int j = 0; j < 8; ++j) acc[i][j] = 0.f;
    for (int kc = 0; kc < 80; kc += 16) {
        __syncthreads();
#pragma unroll
        for (int i = 0; i < 2; ++i) {
            int f4 = t + i * 256;
            *(float4*)(&w_lds[f4 * 4]) = *(const float4*)(We + (size_t)kc * 128 + (size_t)f4 * 4);
        }
        __syncthreads();
#pragma unroll 8
        for (int k = 0; k < 16; ++k) { KSTEP(stage, k, kc + k) }
    }
#pragma unroll
    for (int i = 0; i < 4; ++i)
#pragma unroll
        for (int j = 0; j < 8; ++j) h0reg[i][j] = lk(acc[i][j]);
    __syncthreads();
    {
        int q = t & 31, r0 = t >> 5;
#pragma unroll
        for (int rr = r0; rr < 64; rr += 8) {
            int gedge, partner;
            if (rr < 32) { gedge = p0 + rr;        partner = rev[gedge]; }
            else         { partner = p0 + rr - 32; gedge = rev[partner]; }
            int s = src[gedge];
            float4 a = *(const float4*)(sum0 + (size_t)s * 128 + q * 4);
            u16x4 b4 = *(const u16x4*)(h + (size_t)partner * 128 + q * 4);
            stage[rr][q * 4 + 0] = a.x - bf2f(b4[0]);
            stage[rr][q * 4 + 1] = a.y - bf2f(b4[1]);
            stage[rr][q * 4 + 2] = a.z - bf2f(b4[2]);
            stage[rr][q * 4 + 3] = a.w - bf2f(b4[3]);
        }
    }
#pragma unroll
    for (int i = 0; i < 4; ++i)
#pragma unroll
        for (int j = 0; j < 8; ++j) acc[i][j] = 0.f;
    for (int kc = 0; kc < 128; kc += 32) {
        __syncthreads();
#pragma unroll
        for (int i = 0; i < 4; ++i) {
            int f4 = t + i * 256;
            *(float4*)(&w_lds[f4 * 4]) = *(const float4*)(Wu + (size_t)kc * 128 + (size_t)f4 * 4);
        }
        __syncthreads();
#pragma unroll 8
        for (int k = 0; k < 32; ++k) { KSTEP(stage, k, kc + k) }
    }
#pragma unroll
    for (int i = 0; i < 4; ++i) {
        int gedge = eid_lds[et4 + i];
        size_t base = (size_t)gedge * 128 + ct8;
        u16x8 o;
#pragma unroll
        for (int j = 0; j < 8; ++j) o[j] = f2bf(lk(acc[i][j] + h0reg[i][j]));
        *(u16x8*)(h + base) = o;
    }
}

// ---------------- node transform: hn = leaky([nf|m_node]@W_node + b) ----------
__global__ __launch_bounds__(256) void k_node(const float* __restrict__ node_feat,
                                              const float* __restrict__ m_node,
                                              const float* __restrict__ W,
                                              const float* __restrict__ bias,
                                              float* __restrict__ hn, int Nn) {
    __shared__ float in_lds[64][196];
    __shared__ float w_lds[16 * 128];
    const int t = threadIdx.x;
    const int n0 = blockIdx.x * 64;
    {
        int q = t & 31, r0 = t >> 5;
#pragma unroll
        for (int rr = r0; rr < 64; rr += 8) {
            int n = n0 + rr;
            bool ok = n < Nn;
            const float* nf = node_feat + (size_t)n * 64;
            const float* mn = m_node + (size_t)n * 128;
            for (int qq = q; qq < 48; qq += 32) {
                float4 v; v.x = v.y = v.z = v.w = 0.f;
                if (ok) {
                    if (qq < 16) v = *(const float4*)(nf + qq * 4);
                    else         v = *(const float4*)(mn + (qq - 16) * 4);
                }
                *(float4*)(&in_lds[rr][qq * 4]) = v;
            }
        }
    }
    float acc[4][8];
#pragma unroll
    for (int i = 0; i < 4; ++i)
#pragma unroll
        for (int j = 0; j < 8; ++j) acc[i][j] = 0.f;
    const int et4 = (t >> 4) * 4;
    const int ct8 = (t & 15) * 8;
    for (int kc = 0; kc < 192; kc += 16) {
        __syncthreads();
#pragma unroll
        for (int i = 0; i < 2; ++i) {
            int f4 = t + i * 256;
            *(float4*)(&w_lds[f4 * 4]) = *(const float4*)(W + (size_t)kc * 128 + (size_t)f4 * 4);
        }
        __syncthreads();
#pragma unroll 8
        for (int k = 0; k < 16; ++k) { KSTEP(in_lds, k, kc + k) }
    }
    float4 b0 = *(const float4*)(bias + ct8);
    float4 b1 = *(const float4*)(bias + ct8 + 4);
    __syncthreads();
#pragma unroll
    for (int i = 0; i < 4; ++i) {
        int row = n0 + et4 + i;
        if (row >= Nn) break;
        size_t base = (size_t)row * 128 + ct8;
        float4 o0, o1;
        o0.x = lk(acc[i][0] + b0.x); o0.y = lk(acc[i][1] + b0.y);
        o0.z = lk(acc[i][2] + b0.z); o0.w = lk(acc[i][3] + b0.w);
        o1.x = lk(acc[i][4] + b1.x); o1.y = lk(acc[i][5] + b1.y);
        o1.z = lk(acc[i][6] + b1.z); o1.w = lk(acc[i][7] + b1.w);
        *(float4*)(hn + base) = o0;
        *(float4*)(hn + base + 4) = o1;
    }
}

// ---------------- graph readout ----------------
__device__ __forceinline__ int lbound(const int* __restrict__ a, int n, int key) {
    int lo = 0, hi = n;
    while (lo < hi) { int mid = (lo + hi) >> 1; if (a[mid] < key) lo = mid + 1; else hi = mid; }
    return lo;
}

__global__ __launch_bounds__(256) void k_readout(const float* __restrict__ hn,
                                                 const int* __restrict__ gid,
                                                 const float* __restrict__ extra,
                                                 float* __restrict__ x, int Nn) {
    int b = blockIdx.x;
    int t = threadIdx.x;
    int lo = lbound(gid, Nn, b);
    int hi = lbound(gid, Nn, b + 1);
    if (t < 128) {
        float acc = 0.f;
        int n = lo;
        for (; n + 3 < hi; n += 4) {
            acc += hn[(size_t)n * 128 + t] + hn[(size_t)(n + 1) * 128 + t]
                 + hn[(size_t)(n + 2) * 128 + t] + hn[(size_t)(n + 3) * 128 + t];
        }
        for (; n < hi; ++n) acc += hn[(size_t)n * 128 + t];
        x[(size_t)b * 144 + t] = acc;
    } else if (t < 144) {
        x[(size_t)b * 144 + t] = extra[(size_t)b * 16 + (t - 128)];
    }
}

// ---------------- fused gating + experts ----------------
__global__ __launch_bounds__(256) void k_moe(const float* __restrict__ x,
                                             const float* __restrict__ Wg1, const float* __restrict__ bg1,
                                             const float* __restrict__ Wg2, const float* __restrict__ bg2,
                                             const float* __restrict__ Wg3, const float* __restrict__ bg3,
                                             const float* __restrict__ EW1, const float* __restrict__ Eb1,
                                             const float* __restrict__ EW2, const float* __restrict__ Eb2,
                                             const float* __restrict__ EW3, const float* __restrict__ Eb3,
                                             float* __restrict__ out) {
    __shared__ float xs[144];
    __shared__ float g1s[128], g2s[128];
    __shared__ float e1s[8 * 128], e2s[8 * 128];
    __shared__ float logit_s[8], val_s[8];
    const int b = blockIdx.x;
    const int t = threadIdx.x;
    if (t < 144) xs[t] = x[(size_t)b * 144 + t];
    __syncthreads();
    if (t < 128) {
        float a = bg1[t];
        for (int k = 0; k < 144; ++k) a = fmaf(xs[k], Wg1[k * 128 + t], a);
        g1s[t] = lk(a);
    }
#pragma unroll
    for (int u = 0; u < 4; ++u) {
        int idx = t + u * 256;
        int e = idx >> 7, c = idx & 127;
        float a = Eb1[e * 128 + c];
        const float* w = EW1 + (size_t)e * 144 * 128 + c;
        for (int k = 0; k < 144; ++k) a = fmaf(xs[k], w[(size_t)k * 128], a);
        e1s[idx] = lk(a);
    }
    __syncthreads();
    if (t < 128) {
        float a = bg2[t];
        for (int k = 0; k < 128; ++k) a = fmaf(g1s[k], Wg2[k * 128 + t], a);
        g2s[t] = lk(a);
    }
#pragma unroll
    for (int u = 0; u < 4; ++u) {
        int idx = t + u * 256;
        int e = idx >> 7, c = idx & 127;
        float a = Eb2[e * 128 + c];
        const float* w = EW2 + (size_t)e * 128 * 128 + c;
        const float* e1p = e1s + e * 128;
        for (int k = 0; k < 128; ++k) a = fmaf(e1p[k], w[(size_t)k * 128], a);
        e2s[idx] = lk(a);
    }
    __syncthreads();
    if (t < 8) {
        float a = bg3[t];
        for (int k = 0; k < 128; ++k) a = fmaf(g2s[k], Wg3[k * 8 + t], a);
        logit_s[t] = a;
        float v = Eb3[t];
        const float* w = EW3 + t * 128;
        const float* ep = e2s + t * 128;
        for (int k = 0; k < 128; ++k) v = fmaf(ep[k], w[k], v);
        val_s[t] = v;
    }
    __syncthreads();
    if (t == 0) {
        float mx = logit_s[0];
        for (int e = 1; e < 8; ++e) mx = fmaxf(mx, logit_s[e]);
        float s = 0.f, o = 0.f;
        for (int e = 0; e < 8; ++e) {
            float g = __expf(logit_s[e] - mx);
            s += g;
            o = fmaf(val_s[e], g, o);
        }
        out[b] = o / s;
    }
}

// ---------------------------------------------------------------------------
extern "C" void kernel_launch(void* const* d_in, const int* in_sizes, int n_in,
                              void* d_out, int out_size, void* d_ws, size_t ws_size,
                              hipStream_t stream) {
    const float* node_feat = (const float*)d_in[0];
    const float* edge_feat = (const float*)d_in[1];
    const int*   src       = (const int*)d_in[2];
    const int*   dst       = (const int*)d_in[3];
    const int*   rev       = (const int*)d_in[4];
    const int*   gid       = (const int*)d_in[5];
    const float* extra     = (const float*)d_in[6];
    const float* W_edge    = (const float*)d_in[7];
    const float* W_upd     = (const float*)d_in[8];
    const float* W_node    = (const float*)d_in[9];
    const float* b_node    = (const float*)d_in[10];

    const int Nn = in_sizes[0] / 64;   // 50000
    const int E  = in_sizes[2];        // 640000
    const int Bb = in_sizes[6] / 16;   // 256
    (void)n_in;
    float* out = (float*)d_out;

    uintptr_t p = (uintptr_t)d_ws;
    auto alloc = [&](size_t bytes) -> void* {
        void* r = (void*)p;
        p += (bytes + 255) & ~(size_t)255;
        return r;
    };
    auto al = [](size_t b) { return (b + 255) & ~(size_t)255; };
    const size_t SHb = al((size_t)E * 128 * 2);
    const size_t fixed = al((size_t)Nn * 128 * 4) + al((size_t)Bb * 144 * 4) +
                         al((size_t)(Nn + 1) * 4) + al((size_t)(2 * Nn) * 4) +
                         al((size_t)E * 4) + al(128 * 128 * 2) + al(128 * 96 * 2) + 4096;
    const size_t need_t1 = 2 * SHb + fixed;   // h + h0 (bf16)  ~359 MB
    const size_t need_t2 = SHb + fixed;       // h only, fp32 recompute path

    if (ws_size < need_t2) {
        k_zero_f32<<<(out_size + 255) / 256, 256, 0, stream>>>(out, out_size);
        return;
    }
    const bool T1 = (ws_size >= need_t1);

    u16* h      = (u16*)alloc(SHb);
    u16* h0     = T1 ? (u16*)alloc(SHb) : nullptr;
    float* sum0 = (float*)alloc((size_t)Nn * 128 * sizeof(float)); // reused as hn
    float* xbuf = (float*)alloc((size_t)Bb * 144 * sizeof(float));
    int* off    = (int*)alloc((size_t)(Nn + 1) * sizeof(int));
    int* cc     = (int*)alloc((size_t)(2 * Nn) * sizeof(int));
    int* eidx   = (int*)alloc((size_t)E * sizeof(int));
    u16* wTg    = (u16*)alloc(128 * 128 * sizeof(u16));
    u16* weTg   = (u16*)alloc(128 * 96 * sizeof(u16));
    int* counts = cc;
    int* cursor = cc + Nn;

    k_zero_i32<<<(2 * Nn + 255) / 256, 256, 0, stream>>>(cc, 2 * Nn);

    const int csr_grid = (E + 255) / 256;
    k_count<<<csr_grid, 256, 0, stream>>>(dst, counts, E);
    k_scan<<<1, 1024, 0, stream>>>(counts, off, Nn);
    k_fill<<<csr_grid, 256, 0, stream>>>(dst, off, cursor, eidx, E);

    const int egrid = E / 64;           // 10000
    const int pgrid = (E / 2) / 32;     // 10000
    const int sgrid = (Nn + 3) / 4;

    if (T1) {
        k_prep_wu<<<64, 256, 0, stream>>>(W_upd, wTg);
        k_prep_we<<<48, 256, 0, stream>>>(W_edge, weTg);
        k_edge_init_mfma<<<egrid, 256, 0, stream>>>(node_feat, edge_feat, src, weTg, h0, h);
        for (int r = 0; r < 4; ++r) {
            k_segsum<<<sgrid, 256, 0, stream>>>(h, off, eidx, sum0, Nn);
            k_update_mfma<<<pgrid, 256, 0, stream>>>(h, h0, sum0, src, rev, wTg);
        }
    } else {
        k_edge_init_f32<<<egrid, 256, 0, stream>>>(node_feat, edge_feat, src, W_edge, h);
        for (int r = 0; r < 4; ++r) {
            k_segsum<<<sgrid, 256, 0, stream>>>(h, off, eidx, sum0, Nn);
            k_update_f32_recomp<<<pgrid, 256, 0, stream>>>(h, sum0, src, rev, W_upd,
                                                           node_feat, edge_feat, W_edge);
        }
    }
    k_segsum<<<sgrid, 256, 0, stream>>>(h, off, eidx, sum0, Nn);

    float* hn = sum0;  // alias: k_node reads its own rows before writing them
    k_node<<<(Nn + 63) / 64, 256, 0, stream>>>(node_feat, sum0, W_node, b_node, hn, Nn);
    k_readout<<<Bb, 256, 0, stream>>>(hn, gid, extra, xbuf, Nn);
    k_moe<<<Bb, 256, 0, stream>>>(xbuf,
                                  (const float*)d_in[11], (const float*)d_in[12],
                                  (const float*)d_in[13], (const float*)d_in[14],
                                  (const float*)d_in[15], (const float*)d_in[16],
                                  (const float*)d_in[17], (const float*)d_in[18],
                                  (const float*)d_in[19], (const float*)d_in[20],
                                  (const float*)d_in[21], (const float*)d_in[22],
                                  out);
}

// Round 9
// 1579.761 us; speedup vs baseline: 1.6611x; 1.6611x over previous
//
#include <hip/hip_runtime.h>
#include <stdint.h>
#include <stddef.h>

// ---------------------------------------------------------------------------
// DMPNN on MI355X — round 9: bf16-MFMA fused recompute update.
// Evidence r7/r8: ws in [195,359) MB -> only h (bf16, 164 MB) fits; h0 must be
// recomputed. r8's fp32 recompute kernel: 557us, MfmaUtil 0, VALUBusy 61%,
// 6.7e7 bank-conflict cycles, HBM 11% -> fp32 VALU is the structural limit.
// This round: both GEMMs (h0 recompute K=96-padded, update K=128) run on
// mfma_f32_16x16x32_bf16 inside ONE kernel; h0 lives in registers between them.
// ---------------------------------------------------------------------------

typedef unsigned short u16;
typedef u16 u16x2 __attribute__((ext_vector_type(2)));
typedef u16 u16x4 __attribute__((ext_vector_type(4)));
typedef u16 u16x8 __attribute__((ext_vector_type(8)));
typedef short s16x8 __attribute__((ext_vector_type(8)));
typedef float f32x4_ __attribute__((ext_vector_type(4)));

__device__ __forceinline__ float lk(float x) { return x >= 0.f ? x : 0.01f * x; }

__device__ __forceinline__ float bf2f(u16 u) {
    union { uint32_t i; float f; } v; v.i = ((uint32_t)u) << 16; return v.f;
}
__device__ __forceinline__ u16 f2bf(float f) {   // round-to-nearest-even
    union { float f; uint32_t i; } v; v.f = f;
    uint32_t r = v.i + 0x7FFFu + ((v.i >> 16) & 1u);
    return (u16)(r >> 16);
}

// ---------------- utility ----------------
__global__ void k_zero_i32(int* __restrict__ p, int n) {
    int i = blockIdx.x * blockDim.x + threadIdx.x;
    if (i < n) p[i] = 0;
}
__global__ void k_zero_f32(float* __restrict__ p, int n) {
    int i = blockIdx.x * blockDim.x + threadIdx.x;
    if (i < n) p[i] = 0.f;
}

// W_upd [K=128][N=128] fp32 -> wTg [n][k] bf16 (dense 128x128)
__global__ void k_prep_wu(const float* __restrict__ W, u16* __restrict__ wTg) {
    int i = blockIdx.x * 256 + threadIdx.x;
    if (i < 128 * 128) { int n = i >> 7, k = i & 127; wTg[i] = f2bf(W[k * 128 + n]); }
}
// W_edge [K=80][N=128] fp32 -> weTg [n][k=0..95] bf16, zero pad k>=80
__global__ void k_prep_we(const float* __restrict__ W, u16* __restrict__ weTg) {
    int i = blockIdx.x * 256 + threadIdx.x;
    if (i < 128 * 96) {
        int n = i / 96, k = i - n * 96;
        weTg[i] = (k < 80) ? f2bf(W[k * 128 + n]) : (u16)0;
    }
}

// ---------------- CSR build ----------------
__global__ void k_count(const int* __restrict__ dst, int* __restrict__ counts, int E) {
    int i = blockIdx.x * blockDim.x + threadIdx.x;
    if (i < E) atomicAdd(&counts[dst[i]], 1);
}

__global__ __launch_bounds__(1024) void k_scan(const int* __restrict__ counts,
                                               int* __restrict__ off, int Nn) {
    __shared__ int buf[1024];
    __shared__ int carry_s;
    int t = threadIdx.x;
    if (t == 0) carry_s = 0;
    __syncthreads();
    for (int base = 0; base < Nn; base += 8192) {
        int v[8]; int s = 0;
#pragma unroll
        for (int i = 0; i < 8; ++i) {
            int idx = base + t * 8 + i;
            v[i] = (idx < Nn) ? counts[idx] : 0;
            s += v[i];
        }
        int x = s;
        for (int o = 1; o < 1024; o <<= 1) {
            buf[t] = x; __syncthreads();
            if (t >= o) x += buf[t - o];
            __syncthreads();
        }
        int excl = carry_s + x - s;
#pragma unroll
        for (int i = 0; i < 8; ++i) {
            int idx = base + t * 8 + i;
            if (idx < Nn) off[idx] = excl;
            excl += v[i];
        }
        __syncthreads();
        if (t == 1023) carry_s += x;
        __syncthreads();
    }
    if (t == 0) off[Nn] = carry_s;
}

__global__ void k_fill(const int* __restrict__ dst, const int* __restrict__ off,
                       int* __restrict__ cursor, int* __restrict__ eidx, int E) {
    int i = blockIdx.x * blockDim.x + threadIdx.x;
    if (i < E) {
        int d = dst[i];
        int p = atomicAdd(&cursor[d], 1);
        eidx[off[d] + p] = i;
    }
}

// ---------------- segment sum over bf16 h rows (per-node wave gather) ---------
__global__ __launch_bounds__(256) void k_segsum(const u16* __restrict__ h,
                                                const int* __restrict__ off,
                                                const int* __restrict__ eidx,
                                                float* __restrict__ out, int Nn) {
    int wid = threadIdx.x >> 6;
    int lane = threadIdx.x & 63;
    int n = blockIdx.x * 4 + wid;
    if (n >= Nn) return;
    int lo = off[n], hi = off[n + 1];
    float ax = 0.f, ay = 0.f;
    int j = lo;
    for (; j + 3 < hi; j += 4) {
        int ea = eidx[j], eb = eidx[j + 1], ec = eidx[j + 2], ed = eidx[j + 3];
        u16x2 va = *(const u16x2*)(h + (size_t)ea * 128 + lane * 2);
        u16x2 vb = *(const u16x2*)(h + (size_t)eb * 128 + lane * 2);
        u16x2 vc = *(const u16x2*)(h + (size_t)ec * 128 + lane * 2);
        u16x2 vd = *(const u16x2*)(h + (size_t)ed * 128 + lane * 2);
        ax += (bf2f(va[0]) + bf2f(vb[0])) + (bf2f(vc[0]) + bf2f(vd[0]));
        ay += (bf2f(va[1]) + bf2f(vb[1])) + (bf2f(vc[1]) + bf2f(vd[1]));
    }
    for (; j < hi; ++j) {
        int ea = eidx[j];
        u16x2 va = *(const u16x2*)(h + (size_t)ea * 128 + lane * 2);
        ax += bf2f(va[0]); ay += bf2f(va[1]);
    }
    float2 r; r.x = ax; r.y = ay;
    *(float2*)(out + (size_t)n * 128 + lane * 2) = r;
}

// ===================== MFMA kernels =====================
// Fragment layout (verified vs guide m89): for mfma_f32_16x16x32_bf16 with
// A = W^T slice (16 ncols x 32 k), B[k][col=edge] = m[edge][k]:
// lane l: er=l&15 (edge col / A row), kg=l>>4 (k-octet); D[row=kg*4+r][col=er]
// -> lane holds output ncols {nt*16+kg*4+r} of edge er. Epilogue = u16x4 store.
// LDS strides: 104 bf16 (208B) for K=96 arrays, 136 bf16 (272B) for K=128 —
// both give <=2-way conflicts on b128 reads (free per m136).

// ---- edge init: h = leaky(bf16([nf[src]|ef]) @ bf16(W_edge)) ----
__global__ __launch_bounds__(256) void k_edge_init_mfma(
    const float* __restrict__ node_feat, const float* __restrict__ edge_feat,
    const int* __restrict__ src, const u16* __restrict__ weTg,
    u16* __restrict__ h) {
    __shared__ u16 x0[64][104];     // x0 tile, K padded to 96
    __shared__ u16 wTe[128][104];   // W_edge^T [ncol][k]
    const int t = threadIdx.x;
    const int e0 = blockIdx.x * 64;
    {   // stage wTe (dense [128][96] -> padded rows)
        int n = t >> 1, half = t & 1;
        const u16* gsrc = weTg + n * 96 + half * 48;
        u16* ldst = &wTe[n][half * 48];
#pragma unroll
        for (int i = 0; i < 6; ++i)
            *(u16x8*)(ldst + i * 8) = *(const u16x8*)(gsrc + i * 8);
    }
    {   // stage x0 = [nf[src] | ef] as bf16
        int rloc = t & 63, part = t >> 6;
        int e = e0 + rloc;
        int s = src[e];
        const float* nf = node_feat + (size_t)s * 64;
        const float* ef = edge_feat + (size_t)e * 16;
#pragma unroll
        for (int i = 0; i < 5; ++i) {
            int f = part * 20 + i * 4;
            float4 v;
            if (f < 64) v = *(const float4*)(nf + f);
            else        v = *(const float4*)(ef + (f - 64));
            u16x4 o; o[0] = f2bf(v.x); o[1] = f2bf(v.y); o[2] = f2bf(v.z); o[3] = f2bf(v.w);
            *(u16x4*)(&x0[rloc][f]) = o;
        }
    }
    {   // zero-pad k = 80..95
        int rr = t >> 2, part = t & 3;
        u16x4 z = {0, 0, 0, 0};
        *(u16x4*)(&x0[rr][80 + part * 4]) = z;
    }
    __syncthreads();
    const int w = t >> 6, l = t & 63;
    const int er = l & 15, kg = l >> 4;
    f32x4_ acc[8];
#pragma unroll
    for (int nt = 0; nt < 8; ++nt) { f32x4_ z = {0.f, 0.f, 0.f, 0.f}; acc[nt] = z; }
#pragma unroll
    for (int ks = 0; ks < 3; ++ks) {
        s16x8 bfrag = *(const s16x8*)(&x0[w * 16 + er][ks * 32 + kg * 8]);
#pragma unroll
        for (int nt = 0; nt < 8; ++nt) {
            s16x8 afrag = *(const s16x8*)(&wTe[nt * 16 + er][ks * 32 + kg * 8]);
            acc[nt] = __builtin_amdgcn_mfma_f32_16x16x32_bf16(afrag, bfrag, acc[nt], 0, 0, 0);
        }
    }
    {
        size_t gedge = (size_t)(e0 + w * 16 + er);
        u16* hr = h + gedge * 128;
#pragma unroll
        for (int nt = 0; nt < 8; ++nt) {
            int nc = nt * 16 + kg * 4;
            u16x4 o;
#pragma unroll
            for (int r = 0; r < 4; ++r) o[r] = f2bf(lk(acc[nt][r]));
            *(u16x4*)(hr + nc) = o;
        }
    }
}

// ---- fused in-place paired round update, both GEMMs on MFMA ----
// phase1: h0 = leaky(x0 @ W_edge) recomputed into registers (layout == phase2 D)
// phase2: h[gedge] = bf16(leaky((sum0[src]-h[rev]) @ W_upd + h0reg))
// LDS union: phase1 {x0[64][104], wTe[128][104]} = 39.9KB;
//            phase2 {mw[64][136], wT[128][136]}  = 52.2KB.  (3 blocks/CU)
__global__ __launch_bounds__(256) void k_update_mfma_recomp(
    u16* __restrict__ h, const float* __restrict__ sum0,
    const int* __restrict__ src, const int* __restrict__ rev,
    const u16* __restrict__ wTg, const u16* __restrict__ weTg,
    const float* __restrict__ node_feat, const float* __restrict__ edge_feat) {
    __shared__ __align__(16) u16 smem[64 * 136 + 128 * 136];
    __shared__ int eid[64];
    u16 (*x0)[104]  = (u16(*)[104])smem;
    u16 (*wTe)[104] = (u16(*)[104])(smem + 64 * 104);
    u16 (*mw)[136]  = (u16(*)[136])smem;
    u16 (*wT)[136]  = (u16(*)[136])(smem + 64 * 136);
    const int t = threadIdx.x;
    const int p0 = blockIdx.x * 32;
    const int w = t >> 6, l = t & 63;
    const int er = l & 15, kg = l >> 4;

    // ---- phase 1 staging: x0 rows for this block's 64 edges + wTe ----
    {
        int n = t >> 1, half = t & 1;
        const u16* gsrc = weTg + n * 96 + half * 48;
        u16* ldst = &wTe[n][half * 48];
#pragma unroll
        for (int i = 0; i < 6; ++i)
            *(u16x8*)(ldst + i * 8) = *(const u16x8*)(gsrc + i * 8);
    }
    {
        int rloc = t & 63, part = t >> 6;
        int gedge = (rloc < 32) ? (p0 + rloc) : rev[p0 + rloc - 32];
        if (part == 0) eid[rloc] = gedge;
        int s = src[gedge];
        const float* nf = node_feat + (size_t)s * 64;
        const float* ef = edge_feat + (size_t)gedge * 16;
#pragma unroll
        for (int i = 0; i < 5; ++i) {
            int f = part * 20 + i * 4;
            float4 v;
            if (f < 64) v = *(const float4*)(nf + f);
            else        v = *(const float4*)(ef + (f - 64));
            u16x4 o; o[0] = f2bf(v.x); o[1] = f2bf(v.y); o[2] = f2bf(v.z); o[3] = f2bf(v.w);
            *(u16x4*)(&x0[rloc][f]) = o;
        }
    }
    {
        int rr = t >> 2, part = t & 3;
        u16x4 z = {0, 0, 0, 0};
        *(u16x4*)(&x0[rr][80 + part * 4]) = z;
    }
    __syncthreads();

    // ---- phase 1 MFMA: h0reg = leaky(x0 @ W_edge) ----
    f32x4_ acc[8];
#pragma unroll
    for (int nt = 0; nt < 8; ++nt) { f32x4_ z = {0.f, 0.f, 0.f, 0.f}; acc[nt] = z; }
#pragma unroll
    for (int ks = 0; ks < 3; ++ks) {
        s16x8 bfrag = *(const s16x8*)(&x0[w * 16 + er][ks * 32 + kg * 8]);
#pragma unroll
        for (int nt = 0; nt < 8; ++nt) {
            s16x8 afrag = *(const s16x8*)(&wTe[nt * 16 + er][ks * 32 + kg * 8]);
            acc[nt] = __builtin_amdgcn_mfma_f32_16x16x32_bf16(afrag, bfrag, acc[nt], 0, 0, 0);
        }
    }
    float h0reg[8][4];
#pragma unroll
    for (int nt = 0; nt < 8; ++nt)
#pragma unroll
        for (int r = 0; r < 4; ++r) h0reg[nt][r] = lk(acc[nt][r]);
    __syncthreads();   // phase-1 LDS reads complete before union overwrite

    // ---- phase 2 staging: mw = sum0[src[gedge]] - h[partner], wT ----
    {
        int wr = t >> 1, half = t & 1;
        const u16* gsrc = wTg + wr * 128 + half * 64;
        u16* ldst = &wT[wr][half * 64];
#pragma unroll
        for (int i = 0; i < 8; ++i)
            *(u16x8*)(ldst + i * 8) = *(const u16x8*)(gsrc + i * 8);
    }
    {
        int rr = t >> 2, part = t & 3;
        int gedge, partner;
        if (rr < 32) { gedge = p0 + rr;        partner = rev[gedge]; }
        else         { partner = p0 + rr - 32; gedge = rev[partner]; }
        int s = src[gedge];
        const float* sp = sum0 + (size_t)s * 128 + part * 32;
        const u16* hp = h + (size_t)partner * 128 + part * 32;
#pragma unroll
        for (int i = 0; i < 4; ++i) {
            float4 a0 = *(const float4*)(sp + i * 8);
            float4 a1 = *(const float4*)(sp + i * 8 + 4);
            u16x8 b = *(const u16x8*)(hp + i * 8);
            u16x8 o;
            o[0] = f2bf(a0.x - bf2f(b[0]));
            o[1] = f2bf(a0.y - bf2f(b[1]));
            o[2] = f2bf(a0.z - bf2f(b[2]));
            o[3] = f2bf(a0.w - bf2f(b[3]));
            o[4] = f2bf(a1.x - bf2f(b[4]));
            o[5] = f2bf(a1.y - bf2f(b[5]));
            o[6] = f2bf(a1.z - bf2f(b[6]));
            o[7] = f2bf(a1.w - bf2f(b[7]));
            *(u16x8*)(&mw[rr][part * 32 + i * 8]) = o;
        }
    }
    __syncthreads();

    // ---- phase 2 MFMA: acc = m @ W_upd (K=128) ----
#pragma unroll
    for (int nt = 0; nt < 8; ++nt) { f32x4_ z = {0.f, 0.f, 0.f, 0.f}; acc[nt] = z; }
#pragma unroll
    for (int ks = 0; ks < 4; ++ks) {
        s16x8 bfrag = *(const s16x8*)(&mw[w * 16 + er][ks * 32 + kg * 8]);
#pragma unroll
        for (int nt = 0; nt < 8; ++nt) {
            s16x8 afrag = *(const s16x8*)(&wT[nt * 16 + er][ks * 32 + kg * 8]);
            acc[nt] = __builtin_amdgcn_mfma_f32_16x16x32_bf16(afrag, bfrag, acc[nt], 0, 0, 0);
        }
    }
    // ---- epilogue: h[gedge] = bf16(leaky(acc + h0reg)) (rows block-exclusive) ----
    {
        int gedge = eid[w * 16 + er];
        u16* hr = h + (size_t)gedge * 128;
#pragma unroll
        for (int nt = 0; nt < 8; ++nt) {
            int nc = nt * 16 + kg * 4;
            u16x4 o;
#pragma unroll
            for (int r = 0; r < 4; ++r) o[r] = f2bf(lk(acc[nt][r] + h0reg[nt][r]));
            *(u16x4*)(hr + nc) = o;
        }
    }
}

// ---------------- node transform: hn = leaky([nf|m_node]@W_node + b) ----------
#define KROW(i, m)                                                                 \
    acc[i][0] = fmaf(m, w0.x, acc[i][0]); acc[i][1] = fmaf(m, w0.y, acc[i][1]);    \
    acc[i][2] = fmaf(m, w0.z, acc[i][2]); acc[i][3] = fmaf(m, w0.w, acc[i][3]);    \
    acc[i][4] = fmaf(m, w1.x, acc[i][4]); acc[i][5] = fmaf(m, w1.y, acc[i][5]);    \
    acc[i][6] = fmaf(m, w1.z, acc[i][6]); acc[i][7] = fmaf(m, w1.w, acc[i][7]);

#define KSTEP(ARR, kk, kabs)                                                       \
    {                                                                              \
        const float m0 = ARR[et4 + 0][kabs];                                       \
        const float m1 = ARR[et4 + 1][kabs];                                       \
        const float m2 = ARR[et4 + 2][kabs];                                       \
        const float m3 = ARR[et4 + 3][kabs];                                       \
        const float4 w0 = *(const float4*)(&w_lds[(kk) * 128 + ct8]);              \
        const float4 w1 = *(const float4*)(&w_lds[(kk) * 128 + ct8 + 4]);          \
        KROW(0, m0) KROW(1, m1) KROW(2, m2) KROW(3, m3)                            \
    }

__global__ __launch_bounds__(256) void k_node(const float* __restrict__ node_feat,
                                              const float* __restrict__ m_node,
                                              const float* __restrict__ W,
                                              const float* __restrict__ bias,
                                              float* __restrict__ hn, int Nn) {
    __shared__ float in_lds[64][196];
    __shared__ float w_lds[16 * 128];
    const int t = threadIdx.x;
    const int n0 = blockIdx.x * 64;
    {
        int q = t & 31, r0 = t >> 5;
#pragma unroll
        for (int rr = r0; rr < 64; rr += 8) {
            int n = n0 + rr;
            bool ok = n < Nn;
            const float* nf = node_feat + (size_t)n * 64;
            const float* mn = m_node + (size_t)n * 128;
            for (int qq = q; qq < 48; qq += 32) {
                float4 v; v.x = v.y = v.z = v.w = 0.f;
                if (ok) {
                    if (qq < 16) v = *(const float4*)(nf + qq * 4);
                    else         v = *(const float4*)(mn + (qq - 16) * 4);
                }
                *(float4*)(&in_lds[rr][qq * 4]) = v;
            }
        }
    }
    float acc[4][8];
#pragma unroll
    for (int i = 0; i < 4; ++i)
#pragma unroll
        for (int j = 0; j < 8; ++j) acc[i][j] = 0.f;
    const int et4 = (t >> 4) * 4;
    const int ct8 = (t & 15) * 8;
    for (int kc = 0; kc < 192; kc += 16) {
        __syncthreads();
#pragma unroll
        for (int i = 0; i < 2; ++i) {
            int f4 = t + i * 256;
            *(float4*)(&w_lds[f4 * 4]) = *(const float4*)(W + (size_t)kc * 128 + (size_t)f4 * 4);
        }
        __syncthreads();
#pragma unroll 8
        for (int k = 0; k < 16; ++k) { KSTEP(in_lds, k, kc + k) }
    }
    float4 b0 = *(const float4*)(bias + ct8);
    float4 b1 = *(const float4*)(bias + ct8 + 4);
    __syncthreads();
#pragma unroll
    for (int i = 0; i < 4; ++i) {
        int row = n0 + et4 + i;
        if (row >= Nn) break;
        size_t base = (size_t)row * 128 + ct8;
        float4 o0, o1;
        o0.x = lk(acc[i][0] + b0.x); o0.y = lk(acc[i][1] + b0.y);
        o0.z = lk(acc[i][2] + b0.z); o0.w = lk(acc[i][3] + b0.w);
        o1.x = lk(acc[i][4] + b1.x); o1.y = lk(acc[i][5] + b1.y);
        o1.z = lk(acc[i][6] + b1.z); o1.w = lk(acc[i][7] + b1.w);
        *(float4*)(hn + base) = o0;
        *(float4*)(hn + base + 4) = o1;
    }
}

// ---------------- graph readout ----------------
__device__ __forceinline__ int lbound(const int* __restrict__ a, int n, int key) {
    int lo = 0, hi = n;
    while (lo < hi) { int mid = (lo + hi) >> 1; if (a[mid] < key) lo = mid + 1; else hi = mid; }
    return lo;
}

__global__ __launch_bounds__(256) void k_readout(const float* __restrict__ hn,
                                                 const int* __restrict__ gid,
                                                 const float* __restrict__ extra,
                                                 float* __restrict__ x, int Nn) {
    int b = blockIdx.x;
    int t = threadIdx.x;
    int lo = lbound(gid, Nn, b);
    int hi = lbound(gid, Nn, b + 1);
    if (t < 128) {
        float acc = 0.f;
        int n = lo;
        for (; n + 3 < hi; n += 4) {
            acc += hn[(size_t)n * 128 + t] + hn[(size_t)(n + 1) * 128 + t]
                 + hn[(size_t)(n + 2) * 128 + t] + hn[(size_t)(n + 3) * 128 + t];
        }
        for (; n < hi; ++n) acc += hn[(size_t)n * 128 + t];
        x[(size_t)b * 144 + t] = acc;
    } else if (t < 144) {
        x[(size_t)b * 144 + t] = extra[(size_t)b * 16 + (t - 128)];
    }
}

// ---------------- fused gating + experts ----------------
__global__ __launch_bounds__(256) void k_moe(const float* __restrict__ x,
                                             const float* __restrict__ Wg1, const float* __restrict__ bg1,
                                             const float* __restrict__ Wg2, const float* __restrict__ bg2,
                                             const float* __restrict__ Wg3, const float* __restrict__ bg3,
                                             const float* __restrict__ EW1, const float* __restrict__ Eb1,
                                             const float* __restrict__ EW2, const float* __restrict__ Eb2,
                                             const float* __restrict__ EW3, const float* __restrict__ Eb3,
                                             float* __restrict__ out) {
    __shared__ float xs[144];
    __shared__ float g1s[128], g2s[128];
    __shared__ float e1s[8 * 128], e2s[8 * 128];
    __shared__ float logit_s[8], val_s[8];
    const int b = blockIdx.x;
    const int t = threadIdx.x;
    if (t < 144) xs[t] = x[(size_t)b * 144 + t];
    __syncthreads();
    if (t < 128) {
        float a = bg1[t];
        for (int k = 0; k < 144; ++k) a = fmaf(xs[k], Wg1[k * 128 + t], a);
        g1s[t] = lk(a);
    }
#pragma unroll
    for (int u = 0; u < 4; ++u) {
        int idx = t + u * 256;
        int e = idx >> 7, c = idx & 127;
        float a = Eb1[e * 128 + c];
        const float* w = EW1 + (size_t)e * 144 * 128 + c;
        for (int k = 0; k < 144; ++k) a = fmaf(xs[k], w[(size_t)k * 128], a);
        e1s[idx] = lk(a);
    }
    __syncthreads();
    if (t < 128) {
        float a = bg2[t];
        for (int k = 0; k < 128; ++k) a = fmaf(g1s[k], Wg2[k * 128 + t], a);
        g2s[t] = lk(a);
    }
#pragma unroll
    for (int u = 0; u < 4; ++u) {
        int idx = t + u * 256;
        int e = idx >> 7, c = idx & 127;
        float a = Eb2[e * 128 + c];
        const float* w = EW2 + (size_t)e * 128 * 128 + c;
        const float* e1p = e1s + e * 128;
        for (int k = 0; k < 128; ++k) a = fmaf(e1p[k], w[(size_t)k * 128], a);
        e2s[idx] = lk(a);
    }
    __syncthreads();
    if (t < 8) {
        float a = bg3[t];
        for (int k = 0; k < 128; ++k) a = fmaf(g2s[k], Wg3[k * 8 + t], a);
        logit_s[t] = a;
        float v = Eb3[t];
        const float* w = EW3 + t * 128;
        const float* ep = e2s + t * 128;
        for (int k = 0; k < 128; ++k) v = fmaf(ep[k], w[k], v);
        val_s[t] = v;
    }
    __syncthreads();
    if (t == 0) {
        float mx = logit_s[0];
        for (int e = 1; e < 8; ++e) mx = fmaxf(mx, logit_s[e]);
        float s = 0.f, o = 0.f;
        for (int e = 0; e < 8; ++e) {
            float g = __expf(logit_s[e] - mx);
            s += g;
            o = fmaf(val_s[e], g, o);
        }
        out[b] = o / s;
    }
}

// ---------------------------------------------------------------------------
extern "C" void kernel_launch(void* const* d_in, const int* in_sizes, int n_in,
                              void* d_out, int out_size, void* d_ws, size_t ws_size,
                              hipStream_t stream) {
    const float* node_feat = (const float*)d_in[0];
    const float* edge_feat = (const float*)d_in[1];
    const int*   src       = (const int*)d_in[2];
    const int*   dst       = (const int*)d_in[3];
    const int*   rev       = (const int*)d_in[4];
    const int*   gid       = (const int*)d_in[5];
    const float* extra     = (const float*)d_in[6];
    const float* W_edge    = (const float*)d_in[7];
    const float* W_upd     = (const float*)d_in[8];
    const float* W_node    = (const float*)d_in[9];
    const float* b_node    = (const float*)d_in[10];

    const int Nn = in_sizes[0] / 64;   // 50000
    const int E  = in_sizes[2];        // 640000
    const int Bb = in_sizes[6] / 16;   // 256
    (void)n_in;
    float* out = (float*)d_out;

    uintptr_t p = (uintptr_t)d_ws;
    auto alloc = [&](size_t bytes) -> void* {
        void* r = (void*)p;
        p += (bytes + 255) & ~(size_t)255;
        return r;
    };
    auto al = [](size_t b) { return (b + 255) & ~(size_t)255; };
    const size_t SHb = al((size_t)E * 128 * 2);
    const size_t fixed = al((size_t)Nn * 128 * 4) + al((size_t)Bb * 144 * 4) +
                         al((size_t)(Nn + 1) * 4) + al((size_t)(2 * Nn) * 4) +
                         al((size_t)E * 4) + al(128 * 128 * 2) + al(128 * 96 * 2) + 4096;
    const size_t need = SHb + fixed;   // ~193 MB (known to fit per r7/r8)

    if (ws_size < need) {
        k_zero_f32<<<(out_size + 255) / 256, 256, 0, stream>>>(out, out_size);
        return;
    }

    u16* h      = (u16*)alloc(SHb);
    float* sum0 = (float*)alloc((size_t)Nn * 128 * sizeof(float)); // reused as hn
    float* xbuf = (float*)alloc((size_t)Bb * 144 * sizeof(float));
    int* off    = (int*)alloc((size_t)(Nn + 1) * sizeof(int));
    int* cc     = (int*)alloc((size_t)(2 * Nn) * sizeof(int));
    int* eidx   = (int*)alloc((size_t)E * sizeof(int));
    u16* wTg    = (u16*)alloc(128 * 128 * sizeof(u16));
    u16* weTg   = (u16*)alloc(128 * 96 * sizeof(u16));
    int* counts = cc;
    int* cursor = cc + Nn;

    k_zero_i32<<<(2 * Nn + 255) / 256, 256, 0, stream>>>(cc, 2 * Nn);

    const int csr_grid = (E + 255) / 256;
    k_count<<<csr_grid, 256, 0, stream>>>(dst, counts, E);
    k_scan<<<1, 1024, 0, stream>>>(counts, off, Nn);
    k_fill<<<csr_grid, 256, 0, stream>>>(dst, off, cursor, eidx, E);

    k_prep_wu<<<64, 256, 0, stream>>>(W_upd, wTg);
    k_prep_we<<<48, 256, 0, stream>>>(W_edge, weTg);

    const int egrid = E / 64;           // 10000
    const int pgrid = (E / 2) / 32;     // 10000
    const int sgrid = (Nn + 3) / 4;

    k_edge_init_mfma<<<egrid, 256, 0, stream>>>(node_feat, edge_feat, src, weTg, h);
    for (int r = 0; r < 4; ++r) {
        k_segsum<<<sgrid, 256, 0, stream>>>(h, off, eidx, sum0, Nn);
        k_update_mfma_recomp<<<pgrid, 256, 0, stream>>>(h, sum0, src, rev, wTg, weTg,
                                                        node_feat, edge_feat);
    }
    k_segsum<<<sgrid, 256, 0, stream>>>(h, off, eidx, sum0, Nn);

    float* hn = sum0;  // alias: k_node reads its own rows before writing them
    k_node<<<(Nn + 63) / 64, 256, 0, stream>>>(node_feat, sum0, W_node, b_node, hn, Nn);
    k_readout<<<Bb, 256, 0, stream>>>(hn, gid, extra, xbuf, Nn);
    k_moe<<<Bb, 256, 0, stream>>>(xbuf,
                                  (const float*)d_in[11], (const float*)d_in[12],
                                  (const float*)d_in[13], (const float*)d_in[14],
                                  (const float*)d_in[15], (const float*)d_in[16],
                                  (const float*)d_in[17], (const float*)d_in[18],
                                  (const float*)d_in[19], (const float*)d_in[20],
                                  (const float*)d_in[21], (const float*)d_in[22],
                                  out);
}